// Round 1
// baseline (3045.138 us; speedup 1.0000x reference)
//
#include <hip/hip_runtime.h>

#define N_NODES 50000
#define N_EDGES 800000
#define HID 128
#define OUT_CH 64

// ---------------- degree count ----------------
__global__ void degree_kernel(const int* __restrict__ dst, float* __restrict__ cnt) {
    int e = blockIdx.x * blockDim.x + threadIdx.x;
    if (e < N_EDGES) atomicAdd(&cnt[dst[e]], 1.0f);
}

// ---------------- scatter-add of 128-ch rows: 32 threads per edge ----------------
__global__ void scatter_kernel(const float* __restrict__ feat,
                               const int* __restrict__ src,
                               const int* __restrict__ dst,
                               float* __restrict__ agg) {
    int gid = blockIdx.x * blockDim.x + threadIdx.x;
    int e  = gid >> 5;   // edge
    int c4 = gid & 31;   // float4 slot (128 ch / 4)
    if (e >= N_EDGES) return;
    int s = src[e], d = dst[e];
    const float4 v = reinterpret_cast<const float4*>(feat + (size_t)s * HID)[c4];
    float* o = agg + (size_t)d * HID + c4 * 4;
    atomicAdd(o + 0, v.x);
    atomicAdd(o + 1, v.y);
    atomicAdd(o + 2, v.z);
    atomicAdd(o + 3, v.w);
}

// ---------------- fused SAGE layer: h = [relu](agg/cnt @ Wl^T + bl + x @ Wr^T) ----------------
__global__ __launch_bounds__(256) void sage_kernel(
    const float* __restrict__ xin,  // [N,128] self features
    const float* __restrict__ agg,  // [N,128] neighbor sums
    const float* __restrict__ cnt,  // [N]
    const float* __restrict__ Wl,   // [128,128]
    const float* __restrict__ bl,   // [128]
    const float* __restrict__ Wr,   // [128,128]
    float* __restrict__ hout,       // [N,128]
    int relu)
{
    __shared__ float s_a[16][HID];
    __shared__ float s_x[16][HID];
    const int node0 = blockIdx.x * 16;
    const int tid = threadIdx.x;

    for (int u = tid; u < 16 * 32; u += 256) {
        int n = u >> 5, c4 = u & 31;
        int node = node0 + n;
        float scale = 1.0f / fmaxf(cnt[node], 1.0f);
        float4 av = reinterpret_cast<const float4*>(agg + (size_t)node * HID)[c4];
        float4 xv = reinterpret_cast<const float4*>(xin + (size_t)node * HID)[c4];
        av.x *= scale; av.y *= scale; av.z *= scale; av.w *= scale;
        reinterpret_cast<float4*>(&s_a[n][0])[c4] = av;
        reinterpret_cast<float4*>(&s_x[n][0])[c4] = xv;
    }
    __syncthreads();

    const int o  = tid & 127;        // output channel
    const int n0 = (tid >> 7) * 8;   // node sub-group (0 or 8)
    float acc[8] = {0, 0, 0, 0, 0, 0, 0, 0};
    for (int k4 = 0; k4 < 32; ++k4) {
        float4 wl = reinterpret_cast<const float4*>(Wl + (size_t)o * HID)[k4];
        float4 wr = reinterpret_cast<const float4*>(Wr + (size_t)o * HID)[k4];
        #pragma unroll
        for (int j = 0; j < 8; ++j) {
            float4 av = reinterpret_cast<const float4*>(&s_a[n0 + j][0])[k4];
            float4 xv = reinterpret_cast<const float4*>(&s_x[n0 + j][0])[k4];
            acc[j] += wl.x * av.x + wl.y * av.y + wl.z * av.z + wl.w * av.w
                    + wr.x * xv.x + wr.y * xv.y + wr.z * xv.z + wr.w * xv.w;
        }
    }
    const float b = bl[o];
    #pragma unroll
    for (int j = 0; j < 8; ++j) {
        float v = acc[j] + b;
        if (relu) v = fmaxf(v, 0.0f);
        hout[(size_t)(node0 + n0 + j) * HID + o] = v;
    }
}

// ---------------- fused layer2 + head + log_softmax ----------------
__global__ __launch_bounds__(256) void final_kernel(
    const float* __restrict__ h1,    // [N,128] self features (layer-2 input)
    const float* __restrict__ agg,   // [N,128] neighbor sums of h1
    const float* __restrict__ cnt,
    const float* __restrict__ Wl2, const float* __restrict__ bl2,
    const float* __restrict__ Wr2,
    const float* __restrict__ Wout, const float* __restrict__ bout,
    float* __restrict__ out)         // [N,64]
{
    __shared__ float s_a[16][HID];
    __shared__ float s_x[16][HID];
    __shared__ float s_h2[16][HID];
    __shared__ float s_lg[16][OUT_CH];
    const int node0 = blockIdx.x * 16;
    const int tid = threadIdx.x;

    for (int u = tid; u < 16 * 32; u += 256) {
        int n = u >> 5, c4 = u & 31;
        int node = node0 + n;
        float scale = 1.0f / fmaxf(cnt[node], 1.0f);
        float4 av = reinterpret_cast<const float4*>(agg + (size_t)node * HID)[c4];
        float4 xv = reinterpret_cast<const float4*>(h1 + (size_t)node * HID)[c4];
        av.x *= scale; av.y *= scale; av.z *= scale; av.w *= scale;
        reinterpret_cast<float4*>(&s_a[n][0])[c4] = av;
        reinterpret_cast<float4*>(&s_x[n][0])[c4] = xv;
    }
    __syncthreads();

    // h2 = agg @ Wl2^T + bl2 + h1 @ Wr2^T   (no relu)
    {
        const int o  = tid & 127;
        const int n0 = (tid >> 7) * 8;
        float acc[8] = {0, 0, 0, 0, 0, 0, 0, 0};
        for (int k4 = 0; k4 < 32; ++k4) {
            float4 wl = reinterpret_cast<const float4*>(Wl2 + (size_t)o * HID)[k4];
            float4 wr = reinterpret_cast<const float4*>(Wr2 + (size_t)o * HID)[k4];
            #pragma unroll
            for (int j = 0; j < 8; ++j) {
                float4 av = reinterpret_cast<const float4*>(&s_a[n0 + j][0])[k4];
                float4 xv = reinterpret_cast<const float4*>(&s_x[n0 + j][0])[k4];
                acc[j] += wl.x * av.x + wl.y * av.y + wl.z * av.z + wl.w * av.w
                        + wr.x * xv.x + wr.y * xv.y + wr.z * xv.z + wr.w * xv.w;
            }
        }
        const float b = bl2[o];
        #pragma unroll
        for (int j = 0; j < 8; ++j)
            s_h2[n0 + j][o] = acc[j] + b;
    }
    __syncthreads();

    // logits = h2 @ Wout^T + bout
    {
        const int o  = tid & 63;        // output channel (64)
        const int n0 = (tid >> 6) * 4;  // 4 groups x 4 nodes
        float acc[4] = {0, 0, 0, 0};
        for (int k4 = 0; k4 < 32; ++k4) {
            float4 w = reinterpret_cast<const float4*>(Wout + (size_t)o * HID)[k4];
            #pragma unroll
            for (int j = 0; j < 4; ++j) {
                float4 hv = reinterpret_cast<const float4*>(&s_h2[n0 + j][0])[k4];
                acc[j] += w.x * hv.x + w.y * hv.y + w.z * hv.z + w.w * hv.w;
            }
        }
        const float b = bout[o];
        #pragma unroll
        for (int j = 0; j < 4; ++j)
            s_lg[n0 + j][o] = acc[j] + b;
    }
    __syncthreads();

    // row-wise log_softmax, one wave (64 lanes) per row
    {
        const int wave = tid >> 6;
        const int lane = tid & 63;
        for (int r = wave; r < 16; r += 4) {
            float v = s_lg[r][lane];
            float m = v;
            for (int off = 32; off; off >>= 1) m = fmaxf(m, __shfl_xor(m, off));
            float ex = expf(v - m);
            float s = ex;
            for (int off = 32; off; off >>= 1) s += __shfl_xor(s, off);
            out[(size_t)(node0 + r) * OUT_CH + lane] = v - m - logf(s);
        }
    }
}

extern "C" void kernel_launch(void* const* d_in, const int* in_sizes, int n_in,
                              void* d_out, int out_size, void* d_ws, size_t ws_size,
                              hipStream_t stream) {
    const float* x    = (const float*)d_in[0];
    const int*   edge = (const int*)d_in[1];     // [2, E] int32
    const int*   src  = edge;
    const int*   dst  = edge + N_EDGES;
    const float* Wl1  = (const float*)d_in[2];
    const float* bl1  = (const float*)d_in[3];
    const float* Wr1  = (const float*)d_in[4];
    const float* Wl2  = (const float*)d_in[5];
    const float* bl2  = (const float*)d_in[6];
    const float* Wr2  = (const float*)d_in[7];
    const float* Wout = (const float*)d_in[8];
    const float* bout = (const float*)d_in[9];
    float* out = (float*)d_out;

    const size_t rowBytes = (size_t)N_NODES * HID * sizeof(float); // 25.6 MB
    char* ws = (char*)d_ws;
    float* agg = (float*)ws;
    float* h1  = (float*)(ws + rowBytes);
    float* cnt = (float*)(ws + 2 * rowBytes);

    hipMemsetAsync(agg, 0, rowBytes, stream);
    hipMemsetAsync(cnt, 0, (size_t)N_NODES * sizeof(float), stream);
    degree_kernel<<<(N_EDGES + 255) / 256, 256, 0, stream>>>(dst, cnt);
    scatter_kernel<<<(N_EDGES * 32) / 256, 256, 0, stream>>>(x, src, dst, agg);
    sage_kernel<<<N_NODES / 16, 256, 0, stream>>>(x, agg, cnt, Wl1, bl1, Wr1, h1, 1);
    hipMemsetAsync(agg, 0, rowBytes, stream);
    scatter_kernel<<<(N_EDGES * 32) / 256, 256, 0, stream>>>(h1, src, dst, agg);
    final_kernel<<<N_NODES / 16, 256, 0, stream>>>(h1, agg, cnt, Wl2, bl2, Wr2,
                                                   Wout, bout, out);
}

// Round 2
// 594.920 us; speedup vs baseline: 5.1186x; 5.1186x over previous
//
#include <hip/hip_runtime.h>

#define N_NODES 50000
#define N_EDGES 800000
#define HID 128
#define OUT_CH 64

// ---------------- int degree histogram ----------------
__global__ void hist_kernel(const int* __restrict__ dst, int* __restrict__ cnt) {
    int e = blockIdx.x * blockDim.x + threadIdx.x;
    if (e < N_EDGES) atomicAdd(&cnt[dst[e]], 1);
}

// ---------------- exclusive scan of degrees -> row_ptr / fill_pos ----------------
// One 1024-thread block; each thread serially scans a ~49-element chunk,
// chunk bases come from a shuffle-based block scan (2 barriers total).
__global__ __launch_bounds__(1024) void scan_kernel(const int* __restrict__ cnt,
                                                    int* __restrict__ row_ptr,
                                                    int* __restrict__ fill_pos) {
    const int tid = threadIdx.x;
    const int CHUNK = (N_NODES + 1023) / 1024;  // 49
    const int beg = tid * CHUNK;
    const int end = (beg + CHUNK < N_NODES) ? beg + CHUNK : N_NODES;
    int sum = 0;
    for (int i = beg; i < end; ++i) sum += cnt[i];

    const int lane = tid & 63, wave = tid >> 6;
    int v = sum;
    #pragma unroll
    for (int off = 1; off < 64; off <<= 1) {
        int t = __shfl_up(v, off);
        if (lane >= off) v += t;
    }
    __shared__ int wsum[16];
    if (lane == 63) wsum[wave] = v;
    __syncthreads();
    if (wave == 0 && lane < 16) {
        int w = wsum[lane];
        #pragma unroll
        for (int off = 1; off < 16; off <<= 1) {
            int t = __shfl_up(w, off);
            if (lane >= off) w += t;
        }
        wsum[lane] = w;
    }
    __syncthreads();
    const int waveBase = (wave > 0) ? wsum[wave - 1] : 0;
    int run = waveBase + v - sum;   // exclusive prefix of this chunk
    for (int i = beg; i < end; ++i) {
        fill_pos[i] = run;
        run += cnt[i];
        row_ptr[i + 1] = run;
    }
    if (tid == 0) row_ptr[0] = 0;
}

// ---------------- bucket fill: edge list sorted by dst ----------------
__global__ void fill_kernel(const int* __restrict__ src, const int* __restrict__ dst,
                            int* __restrict__ fill_pos, int* __restrict__ esrc) {
    int e = blockIdx.x * blockDim.x + threadIdx.x;
    if (e < N_EDGES) {
        int p = atomicAdd(&fill_pos[dst[e]], 1);
        esrc[p] = src[e];
    }
}

// ---------------- gather-based mean aggregation: 1 wave per node ----------------
__global__ __launch_bounds__(256) void gather_agg_kernel(
    const float* __restrict__ feat, const int* __restrict__ row_ptr,
    const int* __restrict__ esrc, float* __restrict__ agg)
{
    const int node = blockIdx.x * 4 + (threadIdx.x >> 6);
    const int lane = threadIdx.x & 63;
    const int beg = row_ptr[node];
    const int end = row_ptr[node + 1];
    float2 a0 = {0.f, 0.f}, a1 = {0.f, 0.f};
    int e = beg;
    for (; e + 2 <= end; e += 2) {
        int s0 = esrc[e], s1 = esrc[e + 1];
        float2 v0 = reinterpret_cast<const float2*>(feat + (size_t)s0 * HID)[lane];
        float2 v1 = reinterpret_cast<const float2*>(feat + (size_t)s1 * HID)[lane];
        a0.x += v0.x; a0.y += v0.y;
        a1.x += v1.x; a1.y += v1.y;
    }
    if (e < end) {
        int s0 = esrc[e];
        float2 v0 = reinterpret_cast<const float2*>(feat + (size_t)s0 * HID)[lane];
        a0.x += v0.x; a0.y += v0.y;
    }
    const float scale = 1.0f / fmaxf((float)(end - beg), 1.0f);
    float2 o;
    o.x = (a0.x + a1.x) * scale;
    o.y = (a0.y + a1.y) * scale;
    reinterpret_cast<float2*>(agg + (size_t)node * HID)[lane] = o;
}

// ---------------- fallback path: fp32 atomic scatter (if ws too small) ----------------
__global__ void scatter_kernel(const float* __restrict__ feat,
                               const int* __restrict__ src,
                               const int* __restrict__ dst,
                               float* __restrict__ agg) {
    int gid = blockIdx.x * blockDim.x + threadIdx.x;
    int e  = gid >> 5;
    int c4 = gid & 31;
    if (e >= N_EDGES) return;
    int s = src[e], d = dst[e];
    const float4 v = reinterpret_cast<const float4*>(feat + (size_t)s * HID)[c4];
    float* o = agg + (size_t)d * HID + c4 * 4;
    atomicAdd(o + 0, v.x);
    atomicAdd(o + 1, v.y);
    atomicAdd(o + 2, v.z);
    atomicAdd(o + 3, v.w);
}

__global__ void scale_kernel(float* __restrict__ agg, const int* __restrict__ cnt) {
    int gid = blockIdx.x * blockDim.x + threadIdx.x;  // over N*32 float4
    int node = gid >> 5, c4 = gid & 31;
    if (node >= N_NODES) return;
    float scale = 1.0f / fmaxf((float)cnt[node], 1.0f);
    float4 v = reinterpret_cast<float4*>(agg + (size_t)node * HID)[c4];
    v.x *= scale; v.y *= scale; v.z *= scale; v.w *= scale;
    reinterpret_cast<float4*>(agg + (size_t)node * HID)[c4] = v;
}

// ---------------- fused SAGE layer: h = [relu](agg @ Wl^T + bl + x @ Wr^T) ----------------
// agg is already mean-scaled.
__global__ __launch_bounds__(256) void sage_kernel(
    const float* __restrict__ xin,
    const float* __restrict__ agg,
    const float* __restrict__ Wl, const float* __restrict__ bl,
    const float* __restrict__ Wr,
    float* __restrict__ hout,
    int relu)
{
    __shared__ float s_a[16][HID];
    __shared__ float s_x[16][HID];
    const int node0 = blockIdx.x * 16;
    const int tid = threadIdx.x;

    for (int u = tid; u < 16 * 32; u += 256) {
        int n = u >> 5, c4 = u & 31;
        int node = node0 + n;
        reinterpret_cast<float4*>(&s_a[n][0])[c4] =
            reinterpret_cast<const float4*>(agg + (size_t)node * HID)[c4];
        reinterpret_cast<float4*>(&s_x[n][0])[c4] =
            reinterpret_cast<const float4*>(xin + (size_t)node * HID)[c4];
    }
    __syncthreads();

    const int o  = tid & 127;
    const int n0 = (tid >> 7) * 8;
    float acc[8] = {0, 0, 0, 0, 0, 0, 0, 0};
    for (int k4 = 0; k4 < 32; ++k4) {
        float4 wl = reinterpret_cast<const float4*>(Wl + (size_t)o * HID)[k4];
        float4 wr = reinterpret_cast<const float4*>(Wr + (size_t)o * HID)[k4];
        #pragma unroll
        for (int j = 0; j < 8; ++j) {
            float4 av = reinterpret_cast<const float4*>(&s_a[n0 + j][0])[k4];
            float4 xv = reinterpret_cast<const float4*>(&s_x[n0 + j][0])[k4];
            acc[j] += wl.x * av.x + wl.y * av.y + wl.z * av.z + wl.w * av.w
                    + wr.x * xv.x + wr.y * xv.y + wr.z * xv.z + wr.w * xv.w;
        }
    }
    const float b = bl[o];
    #pragma unroll
    for (int j = 0; j < 8; ++j) {
        float v = acc[j] + b;
        if (relu) v = fmaxf(v, 0.0f);
        hout[(size_t)(node0 + n0 + j) * HID + o] = v;
    }
}

// ---------------- fused layer2 + head + log_softmax ----------------
__global__ __launch_bounds__(256) void final_kernel(
    const float* __restrict__ h1,
    const float* __restrict__ agg,
    const float* __restrict__ Wl2, const float* __restrict__ bl2,
    const float* __restrict__ Wr2,
    const float* __restrict__ Wout, const float* __restrict__ bout,
    float* __restrict__ out)
{
    __shared__ float s_a[16][HID];
    __shared__ float s_x[16][HID];
    __shared__ float s_h2[16][HID];
    __shared__ float s_lg[16][OUT_CH];
    const int node0 = blockIdx.x * 16;
    const int tid = threadIdx.x;

    for (int u = tid; u < 16 * 32; u += 256) {
        int n = u >> 5, c4 = u & 31;
        int node = node0 + n;
        reinterpret_cast<float4*>(&s_a[n][0])[c4] =
            reinterpret_cast<const float4*>(agg + (size_t)node * HID)[c4];
        reinterpret_cast<float4*>(&s_x[n][0])[c4] =
            reinterpret_cast<const float4*>(h1 + (size_t)node * HID)[c4];
    }
    __syncthreads();

    {
        const int o  = tid & 127;
        const int n0 = (tid >> 7) * 8;
        float acc[8] = {0, 0, 0, 0, 0, 0, 0, 0};
        for (int k4 = 0; k4 < 32; ++k4) {
            float4 wl = reinterpret_cast<const float4*>(Wl2 + (size_t)o * HID)[k4];
            float4 wr = reinterpret_cast<const float4*>(Wr2 + (size_t)o * HID)[k4];
            #pragma unroll
            for (int j = 0; j < 8; ++j) {
                float4 av = reinterpret_cast<const float4*>(&s_a[n0 + j][0])[k4];
                float4 xv = reinterpret_cast<const float4*>(&s_x[n0 + j][0])[k4];
                acc[j] += wl.x * av.x + wl.y * av.y + wl.z * av.z + wl.w * av.w
                        + wr.x * xv.x + wr.y * xv.y + wr.z * xv.z + wr.w * xv.w;
            }
        }
        const float b = bl2[o];
        #pragma unroll
        for (int j = 0; j < 8; ++j)
            s_h2[n0 + j][o] = acc[j] + b;
    }
    __syncthreads();

    {
        const int o  = tid & 63;
        const int n0 = (tid >> 6) * 4;
        float acc[4] = {0, 0, 0, 0};
        for (int k4 = 0; k4 < 32; ++k4) {
            float4 w = reinterpret_cast<const float4*>(Wout + (size_t)o * HID)[k4];
            #pragma unroll
            for (int j = 0; j < 4; ++j) {
                float4 hv = reinterpret_cast<const float4*>(&s_h2[n0 + j][0])[k4];
                acc[j] += w.x * hv.x + w.y * hv.y + w.z * hv.z + w.w * hv.w;
            }
        }
        const float b = bout[o];
        #pragma unroll
        for (int j = 0; j < 4; ++j)
            s_lg[n0 + j][o] = acc[j] + b;
    }
    __syncthreads();

    {
        const int wave = tid >> 6;
        const int lane = tid & 63;
        for (int r = wave; r < 16; r += 4) {
            float v = s_lg[r][lane];
            float m = v;
            for (int off = 32; off; off >>= 1) m = fmaxf(m, __shfl_xor(m, off));
            float ex = expf(v - m);
            float s = ex;
            for (int off = 32; off; off >>= 1) s += __shfl_xor(s, off);
            out[(size_t)(node0 + r) * OUT_CH + lane] = v - m - logf(s);
        }
    }
}

extern "C" void kernel_launch(void* const* d_in, const int* in_sizes, int n_in,
                              void* d_out, int out_size, void* d_ws, size_t ws_size,
                              hipStream_t stream) {
    const float* x    = (const float*)d_in[0];
    const int*   edge = (const int*)d_in[1];
    const int*   src  = edge;
    const int*   dst  = edge + N_EDGES;
    const float* Wl1  = (const float*)d_in[2];
    const float* bl1  = (const float*)d_in[3];
    const float* Wr1  = (const float*)d_in[4];
    const float* Wl2  = (const float*)d_in[5];
    const float* bl2  = (const float*)d_in[6];
    const float* Wr2  = (const float*)d_in[7];
    const float* Wout = (const float*)d_in[8];
    const float* bout = (const float*)d_in[9];
    float* out = (float*)d_out;

    const size_t rowBytes = (size_t)N_NODES * HID * sizeof(float);  // 25.6 MB
    char* ws = (char*)d_ws;
    float* agg     = (float*)ws;                                    // rowBytes
    float* h1      = (float*)(ws + rowBytes);                       // rowBytes
    int*   cnt     = (int*)(ws + 2 * rowBytes);                     // N*4
    int*   row_ptr = (int*)(ws + 2 * rowBytes + (size_t)N_NODES * 4);          // (N+1)*4
    int*   fillp   = (int*)(ws + 2 * rowBytes + (size_t)(2 * N_NODES + 2) * 4); // N*4
    int*   esrc    = (int*)(ws + 2 * rowBytes + (size_t)(3 * N_NODES + 2) * 4); // E*4

    const size_t need = 2 * rowBytes + (size_t)(3 * N_NODES + 2) * 4 + (size_t)N_EDGES * 4;

    hipMemsetAsync(cnt, 0, (size_t)N_NODES * sizeof(int), stream);
    hist_kernel<<<(N_EDGES + 255) / 256, 256, 0, stream>>>(dst, cnt);

    if (ws_size >= need) {
        // CSR gather path
        scan_kernel<<<1, 1024, 0, stream>>>(cnt, row_ptr, fillp);
        fill_kernel<<<(N_EDGES + 255) / 256, 256, 0, stream>>>(src, dst, fillp, esrc);
        gather_agg_kernel<<<N_NODES / 4, 256, 0, stream>>>(x, row_ptr, esrc, agg);
        sage_kernel<<<N_NODES / 16, 256, 0, stream>>>(x, agg, Wl1, bl1, Wr1, h1, 1);
        gather_agg_kernel<<<N_NODES / 4, 256, 0, stream>>>(h1, row_ptr, esrc, agg);
        final_kernel<<<N_NODES / 16, 256, 0, stream>>>(h1, agg, Wl2, bl2, Wr2,
                                                       Wout, bout, out);
    } else {
        // fallback: atomic scatter path
        hipMemsetAsync(agg, 0, rowBytes, stream);
        scatter_kernel<<<(N_EDGES * 32) / 256, 256, 0, stream>>>(x, src, dst, agg);
        scale_kernel<<<(N_NODES * 32 + 255) / 256, 256, 0, stream>>>(agg, cnt);
        sage_kernel<<<N_NODES / 16, 256, 0, stream>>>(x, agg, Wl1, bl1, Wr1, h1, 1);
        hipMemsetAsync(agg, 0, rowBytes, stream);
        scatter_kernel<<<(N_EDGES * 32) / 256, 256, 0, stream>>>(h1, src, dst, agg);
        scale_kernel<<<(N_NODES * 32 + 255) / 256, 256, 0, stream>>>(agg, cnt);
        final_kernel<<<N_NODES / 16, 256, 0, stream>>>(h1, agg, Wl2, bl2, Wr2,
                                                       Wout, bout, out);
    }
}

// Round 3
// 378.418 us; speedup vs baseline: 8.0470x; 1.5721x over previous
//
#include <hip/hip_runtime.h>

#define N_NODES 50000
#define N_EDGES 800000
#define HID 128
#define OUT_CH 64
#define LDA 264   // LDS row stride in bf16 elems (256 + 8 pad)

typedef __attribute__((ext_vector_type(8))) short bf16x8;
typedef __attribute__((ext_vector_type(4))) float f32x4;

__device__ __forceinline__ float bf2f(unsigned int bits16) {
    return __uint_as_float(bits16 << 16);
}
__device__ __forceinline__ unsigned short f2bf(float f) {
    unsigned int u = __float_as_uint(f);
    u = (u + 0x7fffu + ((u >> 16) & 1u)) >> 16;
    return (unsigned short)u;
}

// ---------------- x fp32 -> A1 self-columns (bf16) ----------------
__global__ __launch_bounds__(256) void convert_x_kernel(const float* __restrict__ x,
                                                        unsigned short* __restrict__ ax1) {
    int gid = blockIdx.x * blockDim.x + threadIdx.x;   // over N*32
    int node = gid >> 5, c4 = gid & 31;
    float4 v = reinterpret_cast<const float4*>(x + (size_t)node * HID)[c4];
    unsigned short* o = ax1 + (size_t)node * 256 + 128 + c4 * 4;
    o[0] = f2bf(v.x); o[1] = f2bf(v.y); o[2] = f2bf(v.z); o[3] = f2bf(v.w);
}

// ---------------- weights -> bf16 concat [Wl|Wr] as [128][256] ----------------
__global__ __launch_bounds__(256) void convert_w_kernel(
    const float* __restrict__ Wl1, const float* __restrict__ Wr1,
    const float* __restrict__ Wl2, const float* __restrict__ Wr2,
    unsigned short* __restrict__ wcat1, unsigned short* __restrict__ wcat2) {
    int gid = blockIdx.x * blockDim.x + threadIdx.x;   // over 2*128*256
    int layer = gid >> 15;
    int idx = gid & 32767;
    int n = idx >> 8, k = idx & 255;
    const float* Wl = layer ? Wl2 : Wl1;
    const float* Wr = layer ? Wr2 : Wr1;
    float v = (k < 128) ? Wl[(size_t)n * HID + k] : Wr[(size_t)n * HID + (k - 128)];
    (layer ? wcat2 : wcat1)[idx] = f2bf(v);
}

// ---------------- degree histogram ----------------
__global__ void hist_kernel(const int* __restrict__ dst, int* __restrict__ cnt) {
    int e = blockIdx.x * blockDim.x + threadIdx.x;
    if (e < N_EDGES) atomicAdd(&cnt[dst[e]], 1);
}

// ---------------- scan: cnt -> (cnt := exclusive prefix cursors, row_ptr) ----------------
__global__ __launch_bounds__(1024) void scan_kernel(int* __restrict__ cnt,
                                                    int* __restrict__ row_ptr) {
    const int tid = threadIdx.x;
    const int CHUNK = (N_NODES + 1023) / 1024;   // 49
    const int beg = tid * CHUNK;
    const int end = (beg + CHUNK < N_NODES) ? beg + CHUNK : N_NODES;
    int sum = 0;
    for (int i = beg; i < end; ++i) sum += cnt[i];

    const int lane = tid & 63, wave = tid >> 6;
    int v = sum;
    #pragma unroll
    for (int off = 1; off < 64; off <<= 1) {
        int t = __shfl_up(v, off);
        if (lane >= off) v += t;
    }
    __shared__ int wsum[16];
    if (lane == 63) wsum[wave] = v;
    __syncthreads();
    if (wave == 0 && lane < 16) {
        int w = wsum[lane];
        #pragma unroll
        for (int off = 1; off < 16; off <<= 1) {
            int t = __shfl_up(w, off);
            if (lane >= off) w += t;
        }
        wsum[lane] = w;
    }
    __syncthreads();
    const int waveBase = (wave > 0) ? wsum[wave - 1] : 0;
    int run = waveBase + v - sum;
    for (int i = beg; i < end; ++i) {
        int c = cnt[i];
        cnt[i] = run;            // fill cursor
        run += c;
        row_ptr[i + 1] = run;
    }
    if (tid == 0) row_ptr[0] = 0;
}

// ---------------- bucket fill (cnt used as cursors) ----------------
__global__ void fill_kernel(const int* __restrict__ src, const int* __restrict__ dst,
                            int* __restrict__ cursor, int* __restrict__ esrc) {
    int e = blockIdx.x * blockDim.x + threadIdx.x;
    if (e < N_EDGES) {
        int p = atomicAdd(&cursor[dst[e]], 1);
        esrc[p] = src[e];
    }
}

// ---------------- gather mean-agg in bf16: 1 wave per node ----------------
// feat: row base of self features (stride 256 elems); agg: row base of dest (stride 256)
__global__ __launch_bounds__(256) void gather_kernel(
    const unsigned short* __restrict__ feat, const int* __restrict__ row_ptr,
    const int* __restrict__ esrc, unsigned short* __restrict__ agg)
{
    const int node = blockIdx.x * 4 + (threadIdx.x >> 6);
    const int lane = threadIdx.x & 63;
    const int beg = row_ptr[node];
    const int end = row_ptr[node + 1];
    float a0 = 0, b0 = 0, a1 = 0, b1 = 0, a2 = 0, b2 = 0, a3 = 0, b3 = 0;
    int e = beg;
    for (; e + 4 <= end; e += 4) {
        int s0 = esrc[e], s1 = esrc[e + 1], s2 = esrc[e + 2], s3 = esrc[e + 3];
        unsigned int u0 = *reinterpret_cast<const unsigned int*>(feat + (size_t)s0 * 256 + 2 * lane);
        unsigned int u1 = *reinterpret_cast<const unsigned int*>(feat + (size_t)s1 * 256 + 2 * lane);
        unsigned int u2 = *reinterpret_cast<const unsigned int*>(feat + (size_t)s2 * 256 + 2 * lane);
        unsigned int u3 = *reinterpret_cast<const unsigned int*>(feat + (size_t)s3 * 256 + 2 * lane);
        a0 += bf2f(u0 & 0xffffu); b0 += bf2f(u0 >> 16);
        a1 += bf2f(u1 & 0xffffu); b1 += bf2f(u1 >> 16);
        a2 += bf2f(u2 & 0xffffu); b2 += bf2f(u2 >> 16);
        a3 += bf2f(u3 & 0xffffu); b3 += bf2f(u3 >> 16);
    }
    for (; e < end; ++e) {
        int s0 = esrc[e];
        unsigned int u0 = *reinterpret_cast<const unsigned int*>(feat + (size_t)s0 * 256 + 2 * lane);
        a0 += bf2f(u0 & 0xffffu); b0 += bf2f(u0 >> 16);
    }
    const float scale = 1.0f / fmaxf((float)(end - beg), 1.0f);
    float lo = (a0 + a1 + a2 + a3) * scale;
    float hi = (b0 + b1 + b2 + b3) * scale;
    unsigned int o = (unsigned int)f2bf(lo) | ((unsigned int)f2bf(hi) << 16);
    *reinterpret_cast<unsigned int*>(agg + (size_t)node * 256 + 2 * lane) = o;
}

// ---------------- SAGE layer via MFMA: H = relu?(A @ Wcat^T + b) ----------------
// A: [N][256] bf16.  Wcat: [128][256] bf16.  Hout: row base, stride 256, bf16.
__global__ __launch_bounds__(256) void sage_mfma_kernel(
    const unsigned short* __restrict__ A, const unsigned short* __restrict__ Wcat,
    const float* __restrict__ bias, unsigned short* __restrict__ Hout, int relu)
{
    __shared__ unsigned short sA[16 * LDA];
    const int tid = threadIdx.x;
    const int wave = tid >> 6, lane = tid & 63;
    const int m0 = blockIdx.x * 16;

    #pragma unroll
    for (int i = 0; i < 2; ++i) {
        int u = tid + i * 256;
        int r = u >> 5, c = u & 31;
        uint4 v = reinterpret_cast<const uint4*>(A + (size_t)(m0 + r) * 256)[c];
        *reinterpret_cast<uint4*>(&sA[r * LDA + c * 8]) = v;
    }
    __syncthreads();

    const int l15 = lane & 15, lq = lane >> 4;
    const int n0 = wave * 32;
    bf16x8 bfrag[2][8];
    #pragma unroll
    for (int nt = 0; nt < 2; ++nt) {
        const unsigned short* wrow = Wcat + (size_t)(n0 + nt * 16 + l15) * 256;
        #pragma unroll
        for (int ks = 0; ks < 8; ++ks)
            bfrag[nt][ks] = *reinterpret_cast<const bf16x8*>(wrow + ks * 32 + lq * 8);
    }
    f32x4 acc0 = {0.f, 0.f, 0.f, 0.f}, acc1 = {0.f, 0.f, 0.f, 0.f};
    #pragma unroll
    for (int ks = 0; ks < 8; ++ks) {
        bf16x8 af = *reinterpret_cast<const bf16x8*>(&sA[l15 * LDA + ks * 32 + lq * 8]);
        acc0 = __builtin_amdgcn_mfma_f32_16x16x32_bf16(af, bfrag[0][ks], acc0, 0, 0, 0);
        acc1 = __builtin_amdgcn_mfma_f32_16x16x32_bf16(af, bfrag[1][ks], acc1, 0, 0, 0);
    }
    #pragma unroll
    for (int nt = 0; nt < 2; ++nt) {
        const f32x4 a = nt ? acc1 : acc0;
        const int col = n0 + nt * 16 + l15;
        const float bv = bias[col];
        #pragma unroll
        for (int r = 0; r < 4; ++r) {
            float v = a[r] + bv;
            if (relu) v = fmaxf(v, 0.0f);
            Hout[(size_t)(m0 + lq * 4 + r) * 256 + col] = f2bf(v);
        }
    }
}

// ---------------- layer2 GEMM (MFMA) + head + log_softmax ----------------
__global__ __launch_bounds__(256) void final_mfma_kernel(
    const unsigned short* __restrict__ A2, const unsigned short* __restrict__ Wcat2,
    const float* __restrict__ bl2,
    const float* __restrict__ Wout, const float* __restrict__ bout,
    float* __restrict__ out)
{
    __shared__ unsigned short sA[16 * LDA];
    __shared__ float sH[16][132];
    __shared__ float sL[16][OUT_CH];
    const int tid = threadIdx.x;
    const int wave = tid >> 6, lane = tid & 63;
    const int m0 = blockIdx.x * 16;

    #pragma unroll
    for (int i = 0; i < 2; ++i) {
        int u = tid + i * 256;
        int r = u >> 5, c = u & 31;
        uint4 v = reinterpret_cast<const uint4*>(A2 + (size_t)(m0 + r) * 256)[c];
        *reinterpret_cast<uint4*>(&sA[r * LDA + c * 8]) = v;
    }
    __syncthreads();

    const int l15 = lane & 15, lq = lane >> 4;
    const int n0 = wave * 32;
    bf16x8 bfrag[2][8];
    #pragma unroll
    for (int nt = 0; nt < 2; ++nt) {
        const unsigned short* wrow = Wcat2 + (size_t)(n0 + nt * 16 + l15) * 256;
        #pragma unroll
        for (int ks = 0; ks < 8; ++ks)
            bfrag[nt][ks] = *reinterpret_cast<const bf16x8*>(wrow + ks * 32 + lq * 8);
    }
    f32x4 acc0 = {0.f, 0.f, 0.f, 0.f}, acc1 = {0.f, 0.f, 0.f, 0.f};
    #pragma unroll
    for (int ks = 0; ks < 8; ++ks) {
        bf16x8 af = *reinterpret_cast<const bf16x8*>(&sA[l15 * LDA + ks * 32 + lq * 8]);
        acc0 = __builtin_amdgcn_mfma_f32_16x16x32_bf16(af, bfrag[0][ks], acc0, 0, 0, 0);
        acc1 = __builtin_amdgcn_mfma_f32_16x16x32_bf16(af, bfrag[1][ks], acc1, 0, 0, 0);
    }
    #pragma unroll
    for (int nt = 0; nt < 2; ++nt) {
        const f32x4 a = nt ? acc1 : acc0;
        const int col = n0 + nt * 16 + l15;
        const float bv = bl2[col];
        #pragma unroll
        for (int r = 0; r < 4; ++r)
            sH[lq * 4 + r][col] = a[r] + bv;
    }
    __syncthreads();

    // head: logits = h2 @ Wout^T + bout
    {
        const int o = tid & 63;
        const int jb = (tid >> 6) * 4;
        float hacc[4] = {0, 0, 0, 0};
        for (int k4 = 0; k4 < 32; ++k4) {
            float4 w = reinterpret_cast<const float4*>(Wout + (size_t)o * HID)[k4];
            #pragma unroll
            for (int j = 0; j < 4; ++j) {
                float4 h = *reinterpret_cast<const float4*>(&sH[jb + j][k4 * 4]);
                hacc[j] += w.x * h.x + w.y * h.y + w.z * h.z + w.w * h.w;
            }
        }
        const float bv = bout[o];
        #pragma unroll
        for (int j = 0; j < 4; ++j)
            sL[jb + j][o] = hacc[j] + bv;
    }
    __syncthreads();

    // log_softmax: one wave (64 lanes) per row
    for (int r = wave; r < 16; r += 4) {
        float v = sL[r][lane];
        float m = v;
        for (int off = 32; off; off >>= 1) m = fmaxf(m, __shfl_xor(m, off));
        float ex = expf(v - m);
        float s = ex;
        for (int off = 32; off; off >>= 1) s += __shfl_xor(s, off);
        out[(size_t)(m0 + r) * OUT_CH + lane] = v - m - logf(s);
    }
}

extern "C" void kernel_launch(void* const* d_in, const int* in_sizes, int n_in,
                              void* d_out, int out_size, void* d_ws, size_t ws_size,
                              hipStream_t stream) {
    const float* x    = (const float*)d_in[0];
    const int*   edge = (const int*)d_in[1];
    const int*   src  = edge;
    const int*   dst  = edge + N_EDGES;
    const float* Wl1  = (const float*)d_in[2];
    const float* bl1  = (const float*)d_in[3];
    const float* Wr1  = (const float*)d_in[4];
    const float* Wl2  = (const float*)d_in[5];
    const float* bl2  = (const float*)d_in[6];
    const float* Wr2  = (const float*)d_in[7];
    const float* Wout = (const float*)d_in[8];
    const float* bout = (const float*)d_in[9];
    float* out = (float*)d_out;

    char* ws = (char*)d_ws;
    const size_t axBytes = (size_t)N_NODES * 256 * 2;           // 25.6 MB each
    unsigned short* ax1   = (unsigned short*)ws;                 // [N][256]: [agg|x]
    unsigned short* ax2   = (unsigned short*)(ws + axBytes);     // [N][256]: [agg|h1]
    char* p = ws + 2 * axBytes;
    int* cnt     = (int*)p;             p += (size_t)N_NODES * 4;
    int* row_ptr = (int*)p;             p += (size_t)(N_NODES + 1) * 4 + 252;  // pad to keep alignment
    int* esrc    = (int*)p;             p += (size_t)N_EDGES * 4;
    unsigned short* wcat1 = (unsigned short*)p;  p += 128 * 256 * 2;
    unsigned short* wcat2 = (unsigned short*)p;

    hipMemsetAsync(cnt, 0, (size_t)N_NODES * sizeof(int), stream);
    hist_kernel<<<N_EDGES / 256, 256, 0, stream>>>(dst, cnt);
    convert_x_kernel<<<N_NODES * 32 / 256, 256, 0, stream>>>(x, ax1);
    convert_w_kernel<<<2 * 128 * 256 / 256, 256, 0, stream>>>(Wl1, Wr1, Wl2, Wr2, wcat1, wcat2);
    scan_kernel<<<1, 1024, 0, stream>>>(cnt, row_ptr);
    fill_kernel<<<N_EDGES / 256, 256, 0, stream>>>(src, dst, cnt, esrc);

    gather_kernel<<<N_NODES / 4, 256, 0, stream>>>(ax1 + 128, row_ptr, esrc, ax1);
    sage_mfma_kernel<<<N_NODES / 16, 256, 0, stream>>>(ax1, wcat1, bl1, ax2 + 128, 1);
    gather_kernel<<<N_NODES / 4, 256, 0, stream>>>(ax2 + 128, row_ptr, esrc, ax2);
    final_mfma_kernel<<<N_NODES / 16, 256, 0, stream>>>(ax2, wcat2, bl2, Wout, bout, out);
}

// Round 4
// 281.483 us; speedup vs baseline: 10.8182x; 1.3444x over previous
//
#include <hip/hip_runtime.h>

#define N_NODES 50000
#define N_EDGES 800000
#define HID 128
#define OUT_CH 64
#define LDA 264   // LDS A-tile row stride in bf16 elems (256 + 8 pad)
#define SCAN_BLOCKS 196  // ceil(50000/256)

typedef __attribute__((ext_vector_type(8))) short bf16x8;
typedef __attribute__((ext_vector_type(4))) float f32x4;

__device__ __forceinline__ float bf2f(unsigned int bits16) {
    return __uint_as_float(bits16 << 16);
}
__device__ __forceinline__ unsigned short f2bf(float f) {
    unsigned int u = __float_as_uint(f);
    u = (u + 0x7fffu + ((u >> 16) & 1u)) >> 16;
    return (unsigned short)u;
}

// ---------------- convert x -> bf16 [N][128]; also weights -> bf16 [128][256] ----------------
__global__ __launch_bounds__(256) void convert_kernel(
    const float* __restrict__ x, unsigned short* __restrict__ xb,
    const float* __restrict__ Wl1, const float* __restrict__ Wr1,
    const float* __restrict__ Wl2, const float* __restrict__ Wr2,
    unsigned short* __restrict__ wcat1, unsigned short* __restrict__ wcat2)
{
    const int b = blockIdx.x;
    if (b < N_NODES * 32 / 256) {
        int gid = b * 256 + threadIdx.x;          // over N*32
        int node = gid >> 5, c4 = gid & 31;
        float4 v = reinterpret_cast<const float4*>(x + (size_t)node * HID)[c4];
        unsigned short* o = xb + (size_t)node * HID + c4 * 4;
        o[0] = f2bf(v.x); o[1] = f2bf(v.y); o[2] = f2bf(v.z); o[3] = f2bf(v.w);
    } else {
        int idx2 = (b - N_NODES * 32 / 256) * 256 + threadIdx.x;  // over 2*128*256
        int layer = idx2 >> 15;
        int idx = idx2 & 32767;
        int n = idx >> 8, k = idx & 255;
        const float* Wl = layer ? Wl2 : Wl1;
        const float* Wr = layer ? Wr2 : Wr1;
        float v = (k < 128) ? Wl[(size_t)n * HID + k] : Wr[(size_t)n * HID + (k - 128)];
        (layer ? wcat2 : wcat1)[idx] = f2bf(v);
    }
}

// ---------------- degree histogram ----------------
__global__ void hist_kernel(const int* __restrict__ dst, int* __restrict__ cnt) {
    int e = blockIdx.x * blockDim.x + threadIdx.x;
    if (e < N_EDGES) atomicAdd(&cnt[dst[e]], 1);
}

// ---------------- 3-phase exclusive scan of cnt ----------------
__global__ __launch_bounds__(256) void scanA_kernel(const int* __restrict__ cnt,
                                                    int* __restrict__ partial) {
    const int tid = threadIdx.x;
    const int i = blockIdx.x * 256 + tid;
    int v = (i < N_NODES) ? cnt[i] : 0;
    const int lane = tid & 63, wave = tid >> 6;
    int incl = v;
    #pragma unroll
    for (int off = 1; off < 64; off <<= 1) {
        int t = __shfl_up(incl, off);
        if (lane >= off) incl += t;
    }
    __shared__ int wsum[4];
    if (lane == 63) wsum[wave] = incl;
    __syncthreads();
    if (tid == 0) partial[blockIdx.x] = wsum[0] + wsum[1] + wsum[2] + wsum[3];
}

__global__ __launch_bounds__(256) void scanB_kernel(int* __restrict__ partial) {
    const int tid = threadIdx.x;
    int v = (tid < SCAN_BLOCKS) ? partial[tid] : 0;
    const int lane = tid & 63, wave = tid >> 6;
    int incl = v;
    #pragma unroll
    for (int off = 1; off < 64; off <<= 1) {
        int t = __shfl_up(incl, off);
        if (lane >= off) incl += t;
    }
    __shared__ int wsum[4];
    if (lane == 63) wsum[wave] = incl;
    __syncthreads();
    int base = 0;
    if (wave > 0) base += wsum[0];
    if (wave > 1) base += wsum[1];
    if (wave > 2) base += wsum[2];
    if (tid < SCAN_BLOCKS) partial[tid] = base + incl - v;   // exclusive
}

__global__ __launch_bounds__(256) void scanC_kernel(int* __restrict__ cnt,
                                                    const int* __restrict__ partial,
                                                    int* __restrict__ row_ptr) {
    const int tid = threadIdx.x;
    const int i = blockIdx.x * 256 + tid;
    int v = (i < N_NODES) ? cnt[i] : 0;
    const int lane = tid & 63, wave = tid >> 6;
    int incl = v;
    #pragma unroll
    for (int off = 1; off < 64; off <<= 1) {
        int t = __shfl_up(incl, off);
        if (lane >= off) incl += t;
    }
    __shared__ int wsum[4];
    if (lane == 63) wsum[wave] = incl;
    __syncthreads();
    int base = partial[blockIdx.x];
    if (wave > 0) base += wsum[0];
    if (wave > 1) base += wsum[1];
    if (wave > 2) base += wsum[2];
    const int pre = base + incl - v;   // exclusive prefix
    if (i < N_NODES) {
        cnt[i] = pre;                  // fill cursor
        row_ptr[i + 1] = pre + v;
    }
    if (i == 0) row_ptr[0] = 0;
}

// ---------------- bucket fill (cnt used as cursors) ----------------
__global__ void fill_kernel(const int* __restrict__ src, const int* __restrict__ dst,
                            int* __restrict__ cursor, int* __restrict__ esrc) {
    int e = blockIdx.x * blockDim.x + threadIdx.x;
    if (e < N_EDGES) {
        int p = atomicAdd(&cursor[dst[e]], 1);
        esrc[p] = src[e];
    }
}

// ---------------- fused gather + SAGE layer-1 MFMA ----------------
// feat: [N][128] bf16. Out h1: [N][128] bf16.
__global__ __launch_bounds__(256) void sage1_kernel(
    const unsigned short* __restrict__ feat,
    const int* __restrict__ row_ptr, const int* __restrict__ esrc,
    const unsigned short* __restrict__ Wcat, const float* __restrict__ bias,
    unsigned short* __restrict__ Hout)
{
    __shared__ unsigned short sA[16 * LDA];
    const int tid = threadIdx.x;
    const int wave = tid >> 6, lane = tid & 63;
    const int m0 = blockIdx.x * 16;

    // self columns: sA[r][128..255]
    {
        int r = tid >> 4, c = tid & 15;
        uint4 v = reinterpret_cast<const uint4*>(feat + (size_t)(m0 + r) * HID)[c];
        *reinterpret_cast<uint4*>(&sA[r * LDA + 128 + c * 8]) = v;
    }
    // gather mean-agg: wave handles rows wave*4 .. wave*4+3, lane covers ch 2*lane..2*lane+1
    #pragma unroll
    for (int j = 0; j < 4; ++j) {
        const int row = wave * 4 + j;
        const int node = m0 + row;
        const int beg = row_ptr[node], end = row_ptr[node + 1];
        float a0 = 0, b0 = 0, a1 = 0, b1 = 0, a2 = 0, b2 = 0, a3 = 0, b3 = 0;
        int e = beg;
        for (; e + 4 <= end; e += 4) {
            int s0 = esrc[e], s1 = esrc[e + 1], s2 = esrc[e + 2], s3 = esrc[e + 3];
            unsigned int u0 = *reinterpret_cast<const unsigned int*>(feat + (size_t)s0 * HID + 2 * lane);
            unsigned int u1 = *reinterpret_cast<const unsigned int*>(feat + (size_t)s1 * HID + 2 * lane);
            unsigned int u2 = *reinterpret_cast<const unsigned int*>(feat + (size_t)s2 * HID + 2 * lane);
            unsigned int u3 = *reinterpret_cast<const unsigned int*>(feat + (size_t)s3 * HID + 2 * lane);
            a0 += bf2f(u0 & 0xffffu); b0 += bf2f(u0 >> 16);
            a1 += bf2f(u1 & 0xffffu); b1 += bf2f(u1 >> 16);
            a2 += bf2f(u2 & 0xffffu); b2 += bf2f(u2 >> 16);
            a3 += bf2f(u3 & 0xffffu); b3 += bf2f(u3 >> 16);
        }
        for (; e < end; ++e) {
            int s0 = esrc[e];
            unsigned int u0 = *reinterpret_cast<const unsigned int*>(feat + (size_t)s0 * HID + 2 * lane);
            a0 += bf2f(u0 & 0xffffu); b0 += bf2f(u0 >> 16);
        }
        const float scale = 1.0f / fmaxf((float)(end - beg), 1.0f);
        float lo = (a0 + a1 + a2 + a3) * scale;
        float hi = (b0 + b1 + b2 + b3) * scale;
        unsigned int o = (unsigned int)f2bf(lo) | ((unsigned int)f2bf(hi) << 16);
        *reinterpret_cast<unsigned int*>(&sA[row * LDA + 2 * lane]) = o;
    }
    __syncthreads();

    const int l15 = lane & 15, lq = lane >> 4;
    const int n0 = wave * 32;
    bf16x8 bfrag[2][8];
    #pragma unroll
    for (int nt = 0; nt < 2; ++nt) {
        const unsigned short* wrow = Wcat + (size_t)(n0 + nt * 16 + l15) * 256;
        #pragma unroll
        for (int ks = 0; ks < 8; ++ks)
            bfrag[nt][ks] = *reinterpret_cast<const bf16x8*>(wrow + ks * 32 + lq * 8);
    }
    f32x4 acc0 = {0.f, 0.f, 0.f, 0.f}, acc1 = {0.f, 0.f, 0.f, 0.f};
    #pragma unroll
    for (int ks = 0; ks < 8; ++ks) {
        bf16x8 af = *reinterpret_cast<const bf16x8*>(&sA[l15 * LDA + ks * 32 + lq * 8]);
        acc0 = __builtin_amdgcn_mfma_f32_16x16x32_bf16(af, bfrag[0][ks], acc0, 0, 0, 0);
        acc1 = __builtin_amdgcn_mfma_f32_16x16x32_bf16(af, bfrag[1][ks], acc1, 0, 0, 0);
    }
    #pragma unroll
    for (int nt = 0; nt < 2; ++nt) {
        const f32x4 a = nt ? acc1 : acc0;
        const int col = n0 + nt * 16 + l15;
        const float bv = bias[col];
        #pragma unroll
        for (int r = 0; r < 4; ++r) {
            float v = fmaxf(a[r] + bv, 0.0f);      // relu
            Hout[(size_t)(m0 + lq * 4 + r) * HID + col] = f2bf(v);
        }
    }
}

// ---------------- fused gather + layer-2 MFMA + head + log_softmax ----------------
__global__ __launch_bounds__(256) void final_kernel(
    const unsigned short* __restrict__ feat,    // h1 [N][128] bf16
    const int* __restrict__ row_ptr, const int* __restrict__ esrc,
    const unsigned short* __restrict__ Wcat2, const float* __restrict__ bl2,
    const float* __restrict__ Wout, const float* __restrict__ bout,
    float* __restrict__ out)
{
    __shared__ unsigned short sA[16 * LDA];
    __shared__ float sH[16][132];
    __shared__ float sL[16][OUT_CH];
    const int tid = threadIdx.x;
    const int wave = tid >> 6, lane = tid & 63;
    const int m0 = blockIdx.x * 16;

    {
        int r = tid >> 4, c = tid & 15;
        uint4 v = reinterpret_cast<const uint4*>(feat + (size_t)(m0 + r) * HID)[c];
        *reinterpret_cast<uint4*>(&sA[r * LDA + 128 + c * 8]) = v;
    }
    #pragma unroll
    for (int j = 0; j < 4; ++j) {
        const int row = wave * 4 + j;
        const int node = m0 + row;
        const int beg = row_ptr[node], end = row_ptr[node + 1];
        float a0 = 0, b0 = 0, a1 = 0, b1 = 0, a2 = 0, b2 = 0, a3 = 0, b3 = 0;
        int e = beg;
        for (; e + 4 <= end; e += 4) {
            int s0 = esrc[e], s1 = esrc[e + 1], s2 = esrc[e + 2], s3 = esrc[e + 3];
            unsigned int u0 = *reinterpret_cast<const unsigned int*>(feat + (size_t)s0 * HID + 2 * lane);
            unsigned int u1 = *reinterpret_cast<const unsigned int*>(feat + (size_t)s1 * HID + 2 * lane);
            unsigned int u2 = *reinterpret_cast<const unsigned int*>(feat + (size_t)s2 * HID + 2 * lane);
            unsigned int u3 = *reinterpret_cast<const unsigned int*>(feat + (size_t)s3 * HID + 2 * lane);
            a0 += bf2f(u0 & 0xffffu); b0 += bf2f(u0 >> 16);
            a1 += bf2f(u1 & 0xffffu); b1 += bf2f(u1 >> 16);
            a2 += bf2f(u2 & 0xffffu); b2 += bf2f(u2 >> 16);
            a3 += bf2f(u3 & 0xffffu); b3 += bf2f(u3 >> 16);
        }
        for (; e < end; ++e) {
            int s0 = esrc[e];
            unsigned int u0 = *reinterpret_cast<const unsigned int*>(feat + (size_t)s0 * HID + 2 * lane);
            a0 += bf2f(u0 & 0xffffu); b0 += bf2f(u0 >> 16);
        }
        const float scale = 1.0f / fmaxf((float)(end - beg), 1.0f);
        float lo = (a0 + a1 + a2 + a3) * scale;
        float hi = (b0 + b1 + b2 + b3) * scale;
        unsigned int o = (unsigned int)f2bf(lo) | ((unsigned int)f2bf(hi) << 16);
        *reinterpret_cast<unsigned int*>(&sA[row * LDA + 2 * lane]) = o;
    }
    __syncthreads();

    const int l15 = lane & 15, lq = lane >> 4;
    const int n0 = wave * 32;
    bf16x8 bfrag[2][8];
    #pragma unroll
    for (int nt = 0; nt < 2; ++nt) {
        const unsigned short* wrow = Wcat2 + (size_t)(n0 + nt * 16 + l15) * 256;
        #pragma unroll
        for (int ks = 0; ks < 8; ++ks)
            bfrag[nt][ks] = *reinterpret_cast<const bf16x8*>(wrow + ks * 32 + lq * 8);
    }
    f32x4 acc0 = {0.f, 0.f, 0.f, 0.f}, acc1 = {0.f, 0.f, 0.f, 0.f};
    #pragma unroll
    for (int ks = 0; ks < 8; ++ks) {
        bf16x8 af = *reinterpret_cast<const bf16x8*>(&sA[l15 * LDA + ks * 32 + lq * 8]);
        acc0 = __builtin_amdgcn_mfma_f32_16x16x32_bf16(af, bfrag[0][ks], acc0, 0, 0, 0);
        acc1 = __builtin_amdgcn_mfma_f32_16x16x32_bf16(af, bfrag[1][ks], acc1, 0, 0, 0);
    }
    #pragma unroll
    for (int nt = 0; nt < 2; ++nt) {
        const f32x4 a = nt ? acc1 : acc0;
        const int col = n0 + nt * 16 + l15;
        const float bv = bl2[col];
        #pragma unroll
        for (int r = 0; r < 4; ++r)
            sH[lq * 4 + r][col] = a[r] + bv;
    }
    __syncthreads();

    // head: logits = h2 @ Wout^T + bout
    {
        const int o = tid & 63;
        const int jb = (tid >> 6) * 4;
        float hacc[4] = {0, 0, 0, 0};
        for (int k4 = 0; k4 < 32; ++k4) {
            float4 w = reinterpret_cast<const float4*>(Wout + (size_t)o * HID)[k4];
            #pragma unroll
            for (int j = 0; j < 4; ++j) {
                float4 h = *reinterpret_cast<const float4*>(&sH[jb + j][k4 * 4]);
                hacc[j] += w.x * h.x + w.y * h.y + w.z * h.z + w.w * h.w;
            }
        }
        const float bv = bout[o];
        #pragma unroll
        for (int j = 0; j < 4; ++j)
            sL[jb + j][o] = hacc[j] + bv;
    }
    __syncthreads();

    // log_softmax: one wave per row
    for (int r = wave; r < 16; r += 4) {
        float v = sL[r][lane];
        float m = v;
        for (int off = 32; off; off >>= 1) m = fmaxf(m, __shfl_xor(m, off));
        float ex = expf(v - m);
        float s = ex;
        for (int off = 32; off; off >>= 1) s += __shfl_xor(s, off);
        out[(size_t)(m0 + r) * OUT_CH + lane] = v - m - logf(s);
    }
}

extern "C" void kernel_launch(void* const* d_in, const int* in_sizes, int n_in,
                              void* d_out, int out_size, void* d_ws, size_t ws_size,
                              hipStream_t stream) {
    const float* x    = (const float*)d_in[0];
    const int*   edge = (const int*)d_in[1];
    const int*   src  = edge;
    const int*   dst  = edge + N_EDGES;
    const float* Wl1  = (const float*)d_in[2];
    const float* bl1  = (const float*)d_in[3];
    const float* Wr1  = (const float*)d_in[4];
    const float* Wl2  = (const float*)d_in[5];
    const float* bl2  = (const float*)d_in[6];
    const float* Wr2  = (const float*)d_in[7];
    const float* Wout = (const float*)d_in[8];
    const float* bout = (const float*)d_in[9];
    float* out = (float*)d_out;

    char* ws = (char*)d_ws;
    const size_t featBytes = (size_t)N_NODES * HID * 2;          // 12.8 MB
    unsigned short* xb = (unsigned short*)ws;
    unsigned short* h1 = (unsigned short*)(ws + featBytes);
    char* p = ws + 2 * featBytes;
    int* cnt     = (int*)p;   p += (size_t)N_NODES * 4;
    int* row_ptr = (int*)p;   p += (size_t)(N_NODES + 1) * 4 + 252;
    int* partial = (int*)p;   p += 1024;
    int* esrc    = (int*)p;   p += (size_t)N_EDGES * 4;
    unsigned short* wcat1 = (unsigned short*)p;  p += 128 * 256 * 2;
    unsigned short* wcat2 = (unsigned short*)p;

    hipMemsetAsync(cnt, 0, (size_t)N_NODES * sizeof(int), stream);
    hist_kernel<<<N_EDGES / 256, 256, 0, stream>>>(dst, cnt);
    convert_kernel<<<N_NODES * 32 / 256 + 256, 256, 0, stream>>>(
        x, xb, Wl1, Wr1, Wl2, Wr2, wcat1, wcat2);
    scanA_kernel<<<SCAN_BLOCKS, 256, 0, stream>>>(cnt, partial);
    scanB_kernel<<<1, 256, 0, stream>>>(partial);
    scanC_kernel<<<SCAN_BLOCKS, 256, 0, stream>>>(cnt, partial, row_ptr);
    fill_kernel<<<N_EDGES / 256, 256, 0, stream>>>(src, dst, cnt, esrc);

    sage1_kernel<<<N_NODES / 16, 256, 0, stream>>>(xb, row_ptr, esrc, wcat1, bl1, h1);
    final_kernel<<<N_NODES / 16, 256, 0, stream>>>(h1, row_ptr, esrc, wcat2, bl2,
                                                   Wout, bout, out);
}

// Round 5
// 257.982 us; speedup vs baseline: 11.8037x; 1.0911x over previous
//
#include <hip/hip_runtime.h>

#define N_NODES 50000
#define N_EDGES 800000
#define HID 128
#define OUT_CH 64
#define LDA 264   // LDS A-tile row stride in bf16 elems (256 + 8 pad)
#define SCAN_BLOCKS 196  // ceil(50000/256)

typedef __attribute__((ext_vector_type(8))) short bf16x8;
typedef __attribute__((ext_vector_type(4))) float f32x4;

__device__ __forceinline__ float bf2f(unsigned int bits16) {
    return __uint_as_float(bits16 << 16);
}
__device__ __forceinline__ unsigned short f2bf(float f) {
    unsigned int u = __float_as_uint(f);
    u = (u + 0x7fffu + ((u >> 16) & 1u)) >> 16;
    return (unsigned short)u;
}

// ---------------- convert x -> bf16 [N][128]; weights -> bf16 [128][256] ----------------
__global__ __launch_bounds__(256) void convert_kernel(
    const float* __restrict__ x, unsigned short* __restrict__ xb,
    const float* __restrict__ Wl1, const float* __restrict__ Wr1,
    const float* __restrict__ Wl2, const float* __restrict__ Wr2,
    unsigned short* __restrict__ wcat1, unsigned short* __restrict__ wcat2)
{
    const int b = blockIdx.x;
    if (b < N_NODES * 32 / 256) {
        int gid = b * 256 + threadIdx.x;          // over N*32
        int node = gid >> 5, c4 = gid & 31;
        float4 v = reinterpret_cast<const float4*>(x + (size_t)node * HID)[c4];
        unsigned short* o = xb + (size_t)node * HID + c4 * 4;
        o[0] = f2bf(v.x); o[1] = f2bf(v.y); o[2] = f2bf(v.z); o[3] = f2bf(v.w);
    } else {
        int idx2 = (b - N_NODES * 32 / 256) * 256 + threadIdx.x;  // over 2*128*256
        int layer = idx2 >> 15;
        int idx = idx2 & 32767;
        int n = idx >> 8, k = idx & 255;
        const float* Wl = layer ? Wl2 : Wl1;
        const float* Wr = layer ? Wr2 : Wr1;
        float v = (k < 128) ? Wl[(size_t)n * HID + k] : Wr[(size_t)n * HID + (k - 128)];
        (layer ? wcat2 : wcat1)[idx] = f2bf(v);
    }
}

// ---------------- degree histogram ----------------
__global__ void hist_kernel(const int* __restrict__ dst, int* __restrict__ cnt) {
    int e = blockIdx.x * blockDim.x + threadIdx.x;
    if (e < N_EDGES) atomicAdd(&cnt[dst[e]], 1);
}

// ---------------- 3-phase exclusive scan of cnt ----------------
__global__ __launch_bounds__(256) void scanA_kernel(const int* __restrict__ cnt,
                                                    int* __restrict__ partial) {
    const int tid = threadIdx.x;
    const int i = blockIdx.x * 256 + tid;
    int v = (i < N_NODES) ? cnt[i] : 0;
    const int lane = tid & 63, wave = tid >> 6;
    int incl = v;
    #pragma unroll
    for (int off = 1; off < 64; off <<= 1) {
        int t = __shfl_up(incl, off);
        if (lane >= off) incl += t;
    }
    __shared__ int wsum[4];
    if (lane == 63) wsum[wave] = incl;
    __syncthreads();
    if (tid == 0) partial[blockIdx.x] = wsum[0] + wsum[1] + wsum[2] + wsum[3];
}

__global__ __launch_bounds__(256) void scanB_kernel(int* __restrict__ partial) {
    const int tid = threadIdx.x;
    int v = (tid < SCAN_BLOCKS) ? partial[tid] : 0;
    const int lane = tid & 63, wave = tid >> 6;
    int incl = v;
    #pragma unroll
    for (int off = 1; off < 64; off <<= 1) {
        int t = __shfl_up(incl, off);
        if (lane >= off) incl += t;
    }
    __shared__ int wsum[4];
    if (lane == 63) wsum[wave] = incl;
    __syncthreads();
    int base = 0;
    if (wave > 0) base += wsum[0];
    if (wave > 1) base += wsum[1];
    if (wave > 2) base += wsum[2];
    if (tid < SCAN_BLOCKS) partial[tid] = base + incl - v;   // exclusive
}

__global__ __launch_bounds__(256) void scanC_kernel(int* __restrict__ cnt,
                                                    const int* __restrict__ partial,
                                                    int* __restrict__ row_ptr) {
    const int tid = threadIdx.x;
    const int i = blockIdx.x * 256 + tid;
    int v = (i < N_NODES) ? cnt[i] : 0;
    const int lane = tid & 63, wave = tid >> 6;
    int incl = v;
    #pragma unroll
    for (int off = 1; off < 64; off <<= 1) {
        int t = __shfl_up(incl, off);
        if (lane >= off) incl += t;
    }
    __shared__ int wsum[4];
    if (lane == 63) wsum[wave] = incl;
    __syncthreads();
    int base = partial[blockIdx.x];
    if (wave > 0) base += wsum[0];
    if (wave > 1) base += wsum[1];
    if (wave > 2) base += wsum[2];
    const int pre = base + incl - v;
    if (i < N_NODES) {
        cnt[i] = pre;                  // fill cursor
        row_ptr[i + 1] = pre + v;
    }
    if (i == 0) row_ptr[0] = 0;
}

// ---------------- bucket fill (cnt used as cursors) ----------------
__global__ void fill_kernel(const int* __restrict__ src, const int* __restrict__ dst,
                            int* __restrict__ cursor, int* __restrict__ esrc) {
    int e = blockIdx.x * blockDim.x + threadIdx.x;
    if (e < N_EDGES) {
        int p = atomicAdd(&cursor[dst[e]], 1);
        esrc[p] = src[e];
    }
}

// ---------------- wide gather: 16 lanes/row, 4 edges per load-inst, 8 in flight ----------------
// lane = g*16 + c: group g handles edges e+g, chunk c covers channels 8c..8c+7.
// Result: all lanes' acc[0..7] hold the mean for channels 8c..8c+7 (after reduce).
__device__ __forceinline__ void gather_row(
    const unsigned short* __restrict__ feat, const int* __restrict__ esrc,
    int beg, int end, int g, int c, float* acc)
{
    #pragma unroll
    for (int k = 0; k < 8; ++k) acc[k] = 0.0f;
    int e = beg;
    for (; e + 8 <= end; e += 8) {
        #pragma unroll
        for (int b = 0; b < 2; ++b) {
            int s = esrc[e + b * 4 + g];
            uint4 v = *reinterpret_cast<const uint4*>(feat + (size_t)s * HID + c * 8);
            acc[0] += bf2f(v.x & 0xffffu); acc[1] += bf2f(v.x >> 16);
            acc[2] += bf2f(v.y & 0xffffu); acc[3] += bf2f(v.y >> 16);
            acc[4] += bf2f(v.z & 0xffffu); acc[5] += bf2f(v.z >> 16);
            acc[6] += bf2f(v.w & 0xffffu); acc[7] += bf2f(v.w >> 16);
        }
    }
    for (; e < end; e += 4) {
        int idx = e + g;
        if (idx < end) {
            int s = esrc[idx];
            uint4 v = *reinterpret_cast<const uint4*>(feat + (size_t)s * HID + c * 8);
            acc[0] += bf2f(v.x & 0xffffu); acc[1] += bf2f(v.x >> 16);
            acc[2] += bf2f(v.y & 0xffffu); acc[3] += bf2f(v.y >> 16);
            acc[4] += bf2f(v.z & 0xffffu); acc[5] += bf2f(v.z >> 16);
            acc[6] += bf2f(v.w & 0xffffu); acc[7] += bf2f(v.w >> 16);
        }
    }
    const float scale = 1.0f / fmaxf((float)(end - beg), 1.0f);
    #pragma unroll
    for (int k = 0; k < 8; ++k) {
        acc[k] += __shfl_xor(acc[k], 16);
        acc[k] += __shfl_xor(acc[k], 32);
        acc[k] *= scale;
    }
}

// ---------------- fused gather + SAGE layer-1 MFMA ----------------
__global__ __launch_bounds__(256) void sage1_kernel(
    const unsigned short* __restrict__ feat,
    const int* __restrict__ row_ptr, const int* __restrict__ esrc,
    const unsigned short* __restrict__ Wcat, const float* __restrict__ bias,
    unsigned short* __restrict__ Hout)
{
    __shared__ unsigned short sA[16 * LDA];
    const int tid = threadIdx.x;
    const int wave = tid >> 6, lane = tid & 63;
    const int m0 = blockIdx.x * 16;

    // self columns: sA[r][128..255]
    {
        int r = tid >> 4, c = tid & 15;
        uint4 v = reinterpret_cast<const uint4*>(feat + (size_t)(m0 + r) * HID)[c];
        *reinterpret_cast<uint4*>(&sA[r * LDA + 128 + c * 8]) = v;
    }
    const int g = lane >> 4, c = lane & 15;
    #pragma unroll
    for (int j = 0; j < 4; ++j) {
        const int row = wave * 4 + j;
        const int node = m0 + row;
        float acc[8];
        gather_row(feat, esrc, row_ptr[node], row_ptr[node + 1], g, c, acc);
        if (g == 0) {
            uint4 pk;
            pk.x = (unsigned int)f2bf(acc[0]) | ((unsigned int)f2bf(acc[1]) << 16);
            pk.y = (unsigned int)f2bf(acc[2]) | ((unsigned int)f2bf(acc[3]) << 16);
            pk.z = (unsigned int)f2bf(acc[4]) | ((unsigned int)f2bf(acc[5]) << 16);
            pk.w = (unsigned int)f2bf(acc[6]) | ((unsigned int)f2bf(acc[7]) << 16);
            *reinterpret_cast<uint4*>(&sA[row * LDA + c * 8]) = pk;
        }
    }
    __syncthreads();

    const int l15 = lane & 15, lq = lane >> 4;
    const int n0 = wave * 32;
    bf16x8 bfrag[2][8];
    #pragma unroll
    for (int nt = 0; nt < 2; ++nt) {
        const unsigned short* wrow = Wcat + (size_t)(n0 + nt * 16 + l15) * 256;
        #pragma unroll
        for (int ks = 0; ks < 8; ++ks)
            bfrag[nt][ks] = *reinterpret_cast<const bf16x8*>(wrow + ks * 32 + lq * 8);
    }
    f32x4 acc0 = {0.f, 0.f, 0.f, 0.f}, acc1 = {0.f, 0.f, 0.f, 0.f};
    #pragma unroll
    for (int ks = 0; ks < 8; ++ks) {
        bf16x8 af = *reinterpret_cast<const bf16x8*>(&sA[l15 * LDA + ks * 32 + lq * 8]);
        acc0 = __builtin_amdgcn_mfma_f32_16x16x32_bf16(af, bfrag[0][ks], acc0, 0, 0, 0);
        acc1 = __builtin_amdgcn_mfma_f32_16x16x32_bf16(af, bfrag[1][ks], acc1, 0, 0, 0);
    }
    #pragma unroll
    for (int nt = 0; nt < 2; ++nt) {
        const f32x4 a = nt ? acc1 : acc0;
        const int col = n0 + nt * 16 + l15;
        const float bv = bias[col];
        #pragma unroll
        for (int r = 0; r < 4; ++r) {
            float v = fmaxf(a[r] + bv, 0.0f);      // relu
            Hout[(size_t)(m0 + lq * 4 + r) * HID + col] = f2bf(v);
        }
    }
}

// ---------------- fused gather + layer-2 MFMA + head + log_softmax ----------------
__global__ __launch_bounds__(256) void final_kernel(
    const unsigned short* __restrict__ feat,    // h1 [N][128] bf16
    const int* __restrict__ row_ptr, const int* __restrict__ esrc,
    const unsigned short* __restrict__ Wcat2, const float* __restrict__ bl2,
    const float* __restrict__ Wout, const float* __restrict__ bout,
    float* __restrict__ out)
{
    __shared__ __align__(16) char smem[16 * LDA * 2 + 16 * OUT_CH * 4];  // 8448 + 4096
    unsigned short* sA = (unsigned short*)smem;            // phase 1-2
    float (*sH)[132]   = (float(*)[132])smem;              // overlay, phase 3+
    float (*sL)[OUT_CH] = (float(*)[OUT_CH])(smem + 16 * LDA * 2);
    const int tid = threadIdx.x;
    const int wave = tid >> 6, lane = tid & 63;
    const int m0 = blockIdx.x * 16;

    {
        int r = tid >> 4, cc = tid & 15;
        uint4 v = reinterpret_cast<const uint4*>(feat + (size_t)(m0 + r) * HID)[cc];
        *reinterpret_cast<uint4*>(&sA[r * LDA + 128 + cc * 8]) = v;
    }
    const int g = lane >> 4, c = lane & 15;
    #pragma unroll
    for (int j = 0; j < 4; ++j) {
        const int row = wave * 4 + j;
        const int node = m0 + row;
        float acc[8];
        gather_row(feat, esrc, row_ptr[node], row_ptr[node + 1], g, c, acc);
        if (g == 0) {
            uint4 pk;
            pk.x = (unsigned int)f2bf(acc[0]) | ((unsigned int)f2bf(acc[1]) << 16);
            pk.y = (unsigned int)f2bf(acc[2]) | ((unsigned int)f2bf(acc[3]) << 16);
            pk.z = (unsigned int)f2bf(acc[4]) | ((unsigned int)f2bf(acc[5]) << 16);
            pk.w = (unsigned int)f2bf(acc[6]) | ((unsigned int)f2bf(acc[7]) << 16);
            *reinterpret_cast<uint4*>(&sA[row * LDA + c * 8]) = pk;
        }
    }
    __syncthreads();

    const int l15 = lane & 15, lq = lane >> 4;
    const int n0 = wave * 32;
    bf16x8 bfrag[2][8];
    #pragma unroll
    for (int nt = 0; nt < 2; ++nt) {
        const unsigned short* wrow = Wcat2 + (size_t)(n0 + nt * 16 + l15) * 256;
        #pragma unroll
        for (int ks = 0; ks < 8; ++ks)
            bfrag[nt][ks] = *reinterpret_cast<const bf16x8*>(wrow + ks * 32 + lq * 8);
    }
    f32x4 acc0 = {0.f, 0.f, 0.f, 0.f}, acc1 = {0.f, 0.f, 0.f, 0.f};
    #pragma unroll
    for (int ks = 0; ks < 8; ++ks) {
        bf16x8 af = *reinterpret_cast<const bf16x8*>(&sA[l15 * LDA + ks * 32 + lq * 8]);
        acc0 = __builtin_amdgcn_mfma_f32_16x16x32_bf16(af, bfrag[0][ks], acc0, 0, 0, 0);
        acc1 = __builtin_amdgcn_mfma_f32_16x16x32_bf16(af, bfrag[1][ks], acc1, 0, 0, 0);
    }
    __syncthreads();   // all waves done reading sA before sH overlay write

    #pragma unroll
    for (int nt = 0; nt < 2; ++nt) {
        const f32x4 a = nt ? acc1 : acc0;
        const int col = n0 + nt * 16 + l15;
        const float bv = bl2[col];
        #pragma unroll
        for (int r = 0; r < 4; ++r)
            sH[lq * 4 + r][col] = a[r] + bv;
    }
    __syncthreads();

    // head: logits = h2 @ Wout^T + bout
    {
        const int o = tid & 63;
        const int jb = (tid >> 6) * 4;
        float hacc[4] = {0, 0, 0, 0};
        for (int k4 = 0; k4 < 32; ++k4) {
            float4 w = reinterpret_cast<const float4*>(Wout + (size_t)o * HID)[k4];
            #pragma unroll
            for (int j = 0; j < 4; ++j) {
                float4 h = *reinterpret_cast<const float4*>(&sH[jb + j][k4 * 4]);
                hacc[j] += w.x * h.x + w.y * h.y + w.z * h.z + w.w * h.w;
            }
        }
        const float bv = bout[o];
        #pragma unroll
        for (int j = 0; j < 4; ++j)
            sL[jb + j][o] = hacc[j] + bv;
    }
    __syncthreads();

    // log_softmax: one wave per row
    for (int r = wave; r < 16; r += 4) {
        float v = sL[r][lane];
        float m = v;
        for (int off = 32; off; off >>= 1) m = fmaxf(m, __shfl_xor(m, off));
        float ex = expf(v - m);
        float s = ex;
        for (int off = 32; off; off >>= 1) s += __shfl_xor(s, off);
        out[(size_t)(m0 + r) * OUT_CH + lane] = v - m - logf(s);
    }
}

extern "C" void kernel_launch(void* const* d_in, const int* in_sizes, int n_in,
                              void* d_out, int out_size, void* d_ws, size_t ws_size,
                              hipStream_t stream) {
    const float* x    = (const float*)d_in[0];
    const int*   edge = (const int*)d_in[1];
    const int*   src  = edge;
    const int*   dst  = edge + N_EDGES;
    const float* Wl1  = (const float*)d_in[2];
    const float* bl1  = (const float*)d_in[3];
    const float* Wr1  = (const float*)d_in[4];
    const float* Wl2  = (const float*)d_in[5];
    const float* bl2  = (const float*)d_in[6];
    const float* Wr2  = (const float*)d_in[7];
    const float* Wout = (const float*)d_in[8];
    const float* bout = (const float*)d_in[9];
    float* out = (float*)d_out;

    char* ws = (char*)d_ws;
    const size_t featBytes = (size_t)N_NODES * HID * 2;          // 12.8 MB
    unsigned short* xb = (unsigned short*)ws;
    unsigned short* h1 = (unsigned short*)(ws + featBytes);
    char* p = ws + 2 * featBytes;
    int* cnt     = (int*)p;   p += (size_t)N_NODES * 4;
    int* row_ptr = (int*)p;   p += (size_t)(N_NODES + 1) * 4 + 252;
    int* partial = (int*)p;   p += 1024;
    int* esrc    = (int*)p;   p += (size_t)N_EDGES * 4;
    unsigned short* wcat1 = (unsigned short*)p;  p += 128 * 256 * 2;
    unsigned short* wcat2 = (unsigned short*)p;

    hipMemsetAsync(cnt, 0, (size_t)N_NODES * sizeof(int), stream);
    hist_kernel<<<N_EDGES / 256, 256, 0, stream>>>(dst, cnt);
    convert_kernel<<<N_NODES * 32 / 256 + 256, 256, 0, stream>>>(
        x, xb, Wl1, Wr1, Wl2, Wr2, wcat1, wcat2);
    scanA_kernel<<<SCAN_BLOCKS, 256, 0, stream>>>(cnt, partial);
    scanB_kernel<<<1, 256, 0, stream>>>(partial);
    scanC_kernel<<<SCAN_BLOCKS, 256, 0, stream>>>(cnt, partial, row_ptr);
    fill_kernel<<<N_EDGES / 256, 256, 0, stream>>>(src, dst, cnt, esrc);

    sage1_kernel<<<N_NODES / 16, 256, 0, stream>>>(xb, row_ptr, esrc, wcat1, bl1, h1);
    final_kernel<<<N_NODES / 16, 256, 0, stream>>>(h1, row_ptr, esrc, wcat2, bl2,
                                                   Wout, bout, out);
}

// Round 6
// 253.346 us; speedup vs baseline: 12.0197x; 1.0183x over previous
//
#include <hip/hip_runtime.h>

#define N_NODES 50000
#define N_EDGES 800000
#define HID 128
#define OUT_CH 64
#define LDA 264   // LDS A-tile row stride in bf16 elems (256 + 8 pad)
#define SCAN_BLOCKS 196  // ceil(50000/256)

typedef __attribute__((ext_vector_type(8))) short bf16x8;
typedef __attribute__((ext_vector_type(4))) float f32x4;

__device__ __forceinline__ float bf2f(unsigned int bits16) {
    return __uint_as_float(bits16 << 16);
}
__device__ __forceinline__ unsigned short f2bf(float f) {
    unsigned int u = __float_as_uint(f);
    u = (u + 0x7fffu + ((u >> 16) & 1u)) >> 16;
    return (unsigned short)u;
}
__device__ __forceinline__ void acc_u4(float* a, uint4 v) {
    a[0] += bf2f(v.x & 0xffffu); a[1] += bf2f(v.x >> 16);
    a[2] += bf2f(v.y & 0xffffu); a[3] += bf2f(v.y >> 16);
    a[4] += bf2f(v.z & 0xffffu); a[5] += bf2f(v.z >> 16);
    a[6] += bf2f(v.w & 0xffffu); a[7] += bf2f(v.w >> 16);
}

// ---------------- deep-pipelined gather: wave fills 4 rows of sA mean-agg ----------------
// Lane = g*16 + c: group g covers edge slots {b*4+g}, chunk c covers channels 8c..8c+7.
// Edge IDs: one coalesced load per row-chunk (lanes' c indexes 16 consecutive edges),
// distributed to groups via __shfl. Row loads: 8 independent uint4 in flight per pair.
__device__ __forceinline__ void gather4(
    const unsigned short* __restrict__ feat,
    const int* __restrict__ row_ptr, const int* __restrict__ esrc,
    int m0, unsigned short* __restrict__ sA)
{
    const int tid = threadIdx.x;
    const int wave = tid >> 6, lane = tid & 63;
    const int g = lane >> 4, c = lane & 15;
    const int base = m0 + wave * 4;

    int beg[4], deg[4], ids[4];
    int rp0 = row_ptr[base];
    #pragma unroll
    for (int j = 0; j < 4; ++j) {
        int rp1 = row_ptr[base + j + 1];
        beg[j] = rp0; deg[j] = rp1 - rp0; rp0 = rp1;
    }
    #pragma unroll
    for (int j = 0; j < 4; ++j) {
        int idx = beg[j] + c;
        idx = (idx < N_EDGES) ? idx : (N_EDGES - 1);
        ids[j] = esrc[idx];
    }

    float acc[4][8];
    #pragma unroll
    for (int j = 0; j < 4; ++j)
        #pragma unroll
        for (int k = 0; k < 8; ++k) acc[j][k] = 0.0f;

    #pragma unroll
    for (int jp = 0; jp < 2; ++jp) {
        // issue all 8 first-chunk loads for this row pair
        uint4 v[2][4];
        #pragma unroll
        for (int jj = 0; jj < 2; ++jj) {
            const int j = jp * 2 + jj;
            #pragma unroll
            for (int b = 0; b < 4; ++b) {
                int s = __shfl(ids[j], b * 4 + g);
                v[jj][b] = *reinterpret_cast<const uint4*>(feat + (size_t)s * HID + c * 8);
            }
        }
        #pragma unroll
        for (int jj = 0; jj < 2; ++jj) {
            const int j = jp * 2 + jj;
            #pragma unroll
            for (int b = 0; b < 4; ++b) {
                uint4 vv = v[jj][b];
                if (b * 4 + g >= deg[j]) vv = make_uint4(0u, 0u, 0u, 0u);
                acc_u4(acc[j], vv);
            }
        }
        // tails for rows with deg > 16 (wave-uniform loop bounds)
        #pragma unroll
        for (int jj = 0; jj < 2; ++jj) {
            const int j = jp * 2 + jj;
            const int last = beg[j] + deg[j] - 1;
            for (int e0 = 16; e0 < deg[j]; e0 += 16) {
                int idx = beg[j] + e0 + c;
                int id2 = esrc[(idx < last) ? idx : last];
                uint4 w[4];
                #pragma unroll
                for (int b = 0; b < 4; ++b) {
                    int s = __shfl(id2, b * 4 + g);
                    w[b] = *reinterpret_cast<const uint4*>(feat + (size_t)s * HID + c * 8);
                }
                #pragma unroll
                for (int b = 0; b < 4; ++b) {
                    uint4 vv = w[b];
                    if (e0 + b * 4 + g >= deg[j]) vv = make_uint4(0u, 0u, 0u, 0u);
                    acc_u4(acc[j], vv);
                }
            }
        }
    }

    #pragma unroll
    for (int j = 0; j < 4; ++j) {
        const float scale = 1.0f / fmaxf((float)deg[j], 1.0f);
        float r[8];
        #pragma unroll
        for (int k = 0; k < 8; ++k) {
            float t = acc[j][k];
            t += __shfl_xor(t, 16);
            t += __shfl_xor(t, 32);
            r[k] = t * scale;
        }
        if (g == 0) {
            uint4 pk;
            pk.x = (unsigned)f2bf(r[0]) | ((unsigned)f2bf(r[1]) << 16);
            pk.y = (unsigned)f2bf(r[2]) | ((unsigned)f2bf(r[3]) << 16);
            pk.z = (unsigned)f2bf(r[4]) | ((unsigned)f2bf(r[5]) << 16);
            pk.w = (unsigned)f2bf(r[6]) | ((unsigned)f2bf(r[7]) << 16);
            *reinterpret_cast<uint4*>(&sA[(wave * 4 + j) * LDA + c * 8]) = pk;
        }
    }
}

// ---------------- convert x -> bf16 [N][128]; weights -> bf16 [128][256] ----------------
__global__ __launch_bounds__(256) void convert_kernel(
    const float* __restrict__ x, unsigned short* __restrict__ xb,
    const float* __restrict__ Wl1, const float* __restrict__ Wr1,
    const float* __restrict__ Wl2, const float* __restrict__ Wr2,
    unsigned short* __restrict__ wcat1, unsigned short* __restrict__ wcat2)
{
    const int b = blockIdx.x;
    if (b < N_NODES * 32 / 256) {
        int gid = b * 256 + threadIdx.x;          // over N*32
        int node = gid >> 5, c4 = gid & 31;
        float4 v = reinterpret_cast<const float4*>(x + (size_t)node * HID)[c4];
        unsigned short* o = xb + (size_t)node * HID + c4 * 4;
        o[0] = f2bf(v.x); o[1] = f2bf(v.y); o[2] = f2bf(v.z); o[3] = f2bf(v.w);
    } else {
        int idx2 = (b - N_NODES * 32 / 256) * 256 + threadIdx.x;  // over 2*128*256
        int layer = idx2 >> 15;
        int idx = idx2 & 32767;
        int n = idx >> 8, k = idx & 255;
        const float* Wl = layer ? Wl2 : Wl1;
        const float* Wr = layer ? Wr2 : Wr1;
        float v = (k < 128) ? Wl[(size_t)n * HID + k] : Wr[(size_t)n * HID + (k - 128)];
        (layer ? wcat2 : wcat1)[idx] = f2bf(v);
    }
}

// ---------------- degree histogram ----------------
__global__ void hist_kernel(const int* __restrict__ dst, int* __restrict__ cnt) {
    int e = blockIdx.x * blockDim.x + threadIdx.x;
    if (e < N_EDGES) atomicAdd(&cnt[dst[e]], 1);
}

// ---------------- 3-phase exclusive scan of cnt ----------------
__global__ __launch_bounds__(256) void scanA_kernel(const int* __restrict__ cnt,
                                                    int* __restrict__ partial) {
    const int tid = threadIdx.x;
    const int i = blockIdx.x * 256 + tid;
    int v = (i < N_NODES) ? cnt[i] : 0;
    const int lane = tid & 63, wave = tid >> 6;
    int incl = v;
    #pragma unroll
    for (int off = 1; off < 64; off <<= 1) {
        int t = __shfl_up(incl, off);
        if (lane >= off) incl += t;
    }
    __shared__ int wsum[4];
    if (lane == 63) wsum[wave] = incl;
    __syncthreads();
    if (tid == 0) partial[blockIdx.x] = wsum[0] + wsum[1] + wsum[2] + wsum[3];
}

__global__ __launch_bounds__(256) void scanB_kernel(int* __restrict__ partial) {
    const int tid = threadIdx.x;
    int v = (tid < SCAN_BLOCKS) ? partial[tid] : 0;
    const int lane = tid & 63, wave = tid >> 6;
    int incl = v;
    #pragma unroll
    for (int off = 1; off < 64; off <<= 1) {
        int t = __shfl_up(incl, off);
        if (lane >= off) incl += t;
    }
    __shared__ int wsum[4];
    if (lane == 63) wsum[wave] = incl;
    __syncthreads();
    int base = 0;
    if (wave > 0) base += wsum[0];
    if (wave > 1) base += wsum[1];
    if (wave > 2) base += wsum[2];
    if (tid < SCAN_BLOCKS) partial[tid] = base + incl - v;   // exclusive
}

__global__ __launch_bounds__(256) void scanC_kernel(int* __restrict__ cnt,
                                                    const int* __restrict__ partial,
                                                    int* __restrict__ row_ptr) {
    const int tid = threadIdx.x;
    const int i = blockIdx.x * 256 + tid;
    int v = (i < N_NODES) ? cnt[i] : 0;
    const int lane = tid & 63, wave = tid >> 6;
    int incl = v;
    #pragma unroll
    for (int off = 1; off < 64; off <<= 1) {
        int t = __shfl_up(incl, off);
        if (lane >= off) incl += t;
    }
    __shared__ int wsum[4];
    if (lane == 63) wsum[wave] = incl;
    __syncthreads();
    int base = partial[blockIdx.x];
    if (wave > 0) base += wsum[0];
    if (wave > 1) base += wsum[1];
    if (wave > 2) base += wsum[2];
    const int pre = base + incl - v;
    if (i < N_NODES) {
        cnt[i] = pre;                  // fill cursor
        row_ptr[i + 1] = pre + v;
    }
    if (i == 0) row_ptr[0] = 0;
}

// ---------------- bucket fill (cnt used as cursors) ----------------
__global__ void fill_kernel(const int* __restrict__ src, const int* __restrict__ dst,
                            int* __restrict__ cursor, int* __restrict__ esrc) {
    int e = blockIdx.x * blockDim.x + threadIdx.x;
    if (e < N_EDGES) {
        int p = atomicAdd(&cursor[dst[e]], 1);
        esrc[p] = src[e];
    }
}

// ---------------- fused gather + SAGE layer-1 MFMA ----------------
__global__ __launch_bounds__(256) void sage1_kernel(
    const unsigned short* __restrict__ feat,
    const int* __restrict__ row_ptr, const int* __restrict__ esrc,
    const unsigned short* __restrict__ Wcat, const float* __restrict__ bias,
    unsigned short* __restrict__ Hout)
{
    __shared__ unsigned short sA[16 * LDA];
    const int tid = threadIdx.x;
    const int wave = tid >> 6, lane = tid & 63;
    const int m0 = blockIdx.x * 16;

    // self columns: sA[r][128..255]
    {
        int r = tid >> 4, cc = tid & 15;
        uint4 v = reinterpret_cast<const uint4*>(feat + (size_t)(m0 + r) * HID)[cc];
        *reinterpret_cast<uint4*>(&sA[r * LDA + 128 + cc * 8]) = v;
    }
    gather4(feat, row_ptr, esrc, m0, sA);
    __syncthreads();

    const int l15 = lane & 15, lq = lane >> 4;
    const int n0 = wave * 32;
    bf16x8 bfrag[2][8];
    #pragma unroll
    for (int nt = 0; nt < 2; ++nt) {
        const unsigned short* wrow = Wcat + (size_t)(n0 + nt * 16 + l15) * 256;
        #pragma unroll
        for (int ks = 0; ks < 8; ++ks)
            bfrag[nt][ks] = *reinterpret_cast<const bf16x8*>(wrow + ks * 32 + lq * 8);
    }
    f32x4 acc0 = {0.f, 0.f, 0.f, 0.f}, acc1 = {0.f, 0.f, 0.f, 0.f};
    #pragma unroll
    for (int ks = 0; ks < 8; ++ks) {
        bf16x8 af = *reinterpret_cast<const bf16x8*>(&sA[l15 * LDA + ks * 32 + lq * 8]);
        acc0 = __builtin_amdgcn_mfma_f32_16x16x32_bf16(af, bfrag[0][ks], acc0, 0, 0, 0);
        acc1 = __builtin_amdgcn_mfma_f32_16x16x32_bf16(af, bfrag[1][ks], acc1, 0, 0, 0);
    }
    #pragma unroll
    for (int nt = 0; nt < 2; ++nt) {
        const f32x4 a = nt ? acc1 : acc0;
        const int col = n0 + nt * 16 + l15;
        const float bv = bias[col];
        #pragma unroll
        for (int r = 0; r < 4; ++r) {
            float v = fmaxf(a[r] + bv, 0.0f);      // relu
            Hout[(size_t)(m0 + lq * 4 + r) * HID + col] = f2bf(v);
        }
    }
}

// ---------------- fused gather + layer-2 MFMA + head + log_softmax ----------------
__global__ __launch_bounds__(256) void final_kernel(
    const unsigned short* __restrict__ feat,    // h1 [N][128] bf16
    const int* __restrict__ row_ptr, const int* __restrict__ esrc,
    const unsigned short* __restrict__ Wcat2, const float* __restrict__ bl2,
    const float* __restrict__ Wout, const float* __restrict__ bout,
    float* __restrict__ out)
{
    __shared__ __align__(16) char smem[16 * LDA * 2 + 16 * OUT_CH * 4];  // 8448 + 4096
    unsigned short* sA = (unsigned short*)smem;            // phase 1-2
    float (*sH)[132]   = (float(*)[132])smem;              // overlay, phase 3+
    float (*sL)[OUT_CH] = (float(*)[OUT_CH])(smem + 16 * LDA * 2);
    const int tid = threadIdx.x;
    const int wave = tid >> 6, lane = tid & 63;
    const int m0 = blockIdx.x * 16;

    {
        int r = tid >> 4, cc = tid & 15;
        uint4 v = reinterpret_cast<const uint4*>(feat + (size_t)(m0 + r) * HID)[cc];
        *reinterpret_cast<uint4*>(&sA[r * LDA + 128 + cc * 8]) = v;
    }
    gather4(feat, row_ptr, esrc, m0, sA);
    __syncthreads();

    const int l15 = lane & 15, lq = lane >> 4;
    const int n0 = wave * 32;
    bf16x8 bfrag[2][8];
    #pragma unroll
    for (int nt = 0; nt < 2; ++nt) {
        const unsigned short* wrow = Wcat2 + (size_t)(n0 + nt * 16 + l15) * 256;
        #pragma unroll
        for (int ks = 0; ks < 8; ++ks)
            bfrag[nt][ks] = *reinterpret_cast<const bf16x8*>(wrow + ks * 32 + lq * 8);
    }
    f32x4 acc0 = {0.f, 0.f, 0.f, 0.f}, acc1 = {0.f, 0.f, 0.f, 0.f};
    #pragma unroll
    for (int ks = 0; ks < 8; ++ks) {
        bf16x8 af = *reinterpret_cast<const bf16x8*>(&sA[l15 * LDA + ks * 32 + lq * 8]);
        acc0 = __builtin_amdgcn_mfma_f32_16x16x32_bf16(af, bfrag[0][ks], acc0, 0, 0, 0);
        acc1 = __builtin_amdgcn_mfma_f32_16x16x32_bf16(af, bfrag[1][ks], acc1, 0, 0, 0);
    }
    __syncthreads();   // all waves done reading sA before sH overlay write

    #pragma unroll
    for (int nt = 0; nt < 2; ++nt) {
        const f32x4 a = nt ? acc1 : acc0;
        const int col = n0 + nt * 16 + l15;
        const float bv = bl2[col];
        #pragma unroll
        for (int r = 0; r < 4; ++r)
            sH[lq * 4 + r][col] = a[r] + bv;
    }
    __syncthreads();

    // head: logits = h2 @ Wout^T + bout
    {
        const int o = tid & 63;
        const int jb = (tid >> 6) * 4;
        float hacc[4] = {0, 0, 0, 0};
        for (int k4 = 0; k4 < 32; ++k4) {
            float4 w = reinterpret_cast<const float4*>(Wout + (size_t)o * HID)[k4];
            #pragma unroll
            for (int j = 0; j < 4; ++j) {
                float4 h = *reinterpret_cast<const float4*>(&sH[jb + j][k4 * 4]);
                hacc[j] += w.x * h.x + w.y * h.y + w.z * h.z + w.w * h.w;
            }
        }
        const float bv = bout[o];
        #pragma unroll
        for (int j = 0; j < 4; ++j)
            sL[jb + j][o] = hacc[j] + bv;
    }
    __syncthreads();

    // log_softmax: one wave per row
    for (int r = wave; r < 16; r += 4) {
        float v = sL[r][lane];
        float m = v;
        for (int off = 32; off; off >>= 1) m = fmaxf(m, __shfl_xor(m, off));
        float ex = expf(v - m);
        float s = ex;
        for (int off = 32; off; off >>= 1) s += __shfl_xor(s, off);
        out[(size_t)(m0 + r) * OUT_CH + lane] = v - m - logf(s);
    }
}

extern "C" void kernel_launch(void* const* d_in, const int* in_sizes, int n_in,
                              void* d_out, int out_size, void* d_ws, size_t ws_size,
                              hipStream_t stream) {
    const float* x    = (const float*)d_in[0];
    const int*   edge = (const int*)d_in[1];
    const int*   src  = edge;
    const int*   dst  = edge + N_EDGES;
    const float* Wl1  = (const float*)d_in[2];
    const float* bl1  = (const float*)d_in[3];
    const float* Wr1  = (const float*)d_in[4];
    const float* Wl2  = (const float*)d_in[5];
    const float* bl2  = (const float*)d_in[6];
    const float* Wr2  = (const float*)d_in[7];
    const float* Wout = (const float*)d_in[8];
    const float* bout = (const float*)d_in[9];
    float* out = (float*)d_out;

    char* ws = (char*)d_ws;
    const size_t featBytes = (size_t)N_NODES * HID * 2;          // 12.8 MB
    unsigned short* xb = (unsigned short*)ws;
    unsigned short* h1 = (unsigned short*)(ws + featBytes);
    char* p = ws + 2 * featBytes;
    int* cnt     = (int*)p;   p += (size_t)N_NODES * 4;
    int* row_ptr = (int*)p;   p += (size_t)(N_NODES + 1) * 4 + 252;
    int* partial = (int*)p;   p += 1024;
    int* esrc    = (int*)p;   p += (size_t)N_EDGES * 4;
    unsigned short* wcat1 = (unsigned short*)p;  p += 128 * 256 * 2;
    unsigned short* wcat2 = (unsigned short*)p;

    hipMemsetAsync(cnt, 0, (size_t)N_NODES * sizeof(int), stream);
    hist_kernel<<<N_EDGES / 256, 256, 0, stream>>>(dst, cnt);
    convert_kernel<<<N_NODES * 32 / 256 + 256, 256, 0, stream>>>(
        x, xb, Wl1, Wr1, Wl2, Wr2, wcat1, wcat2);
    scanA_kernel<<<SCAN_BLOCKS, 256, 0, stream>>>(cnt, partial);
    scanB_kernel<<<1, 256, 0, stream>>>(partial);
    scanC_kernel<<<SCAN_BLOCKS, 256, 0, stream>>>(cnt, partial, row_ptr);
    fill_kernel<<<N_EDGES / 256, 256, 0, stream>>>(src, dst, cnt, esrc);

    sage1_kernel<<<N_NODES / 16, 256, 0, stream>>>(xb, row_ptr, esrc, wcat1, bl1, h1);
    final_kernel<<<N_NODES / 16, 256, 0, stream>>>(h1, row_ptr, esrc, wcat2, bl2,
                                                   Wout, bout, out);
}